// Round 2
// baseline (2997.748 us; speedup 1.0000x reference)
//
#include <hip/hip_runtime.h>
#include <hip/hip_bf16.h>

#define TT 8
#define NN 10000
#define EE 320000
#define NG 64

__device__ __forceinline__ float sigmf(float x){ return 1.f/(1.f+expf(-x)); }

// ---------- setup ----------
__global__ void k_deg(const int* __restrict__ src, const float* __restrict__ ea, float* __restrict__ deg){
  int e = blockIdx.x*256 + threadIdx.x;
  if(e<EE) atomicAdd(&deg[src[e]], ea[e]);
}

__global__ void k_dis(const float* __restrict__ deg, float* __restrict__ dis){
  int n = blockIdx.x*256+threadIdx.x;
  if(n<NN){ float d=deg[n]; dis[n] = d>0.f ? rsqrtf(d) : 0.f; }
}

__global__ void k_wnorm(const int* __restrict__ src, const int* __restrict__ dst, const float* __restrict__ ea,
                        const float* __restrict__ dis, float* __restrict__ wnorm, int* __restrict__ cnt){
  int e = blockIdx.x*256+threadIdx.x;
  if(e<EE){
    int s=src[e], d=dst[e];
    wnorm[e] = dis[s]*ea[e]*dis[d];
    atomicAdd(&cnt[d],1);
  }
}

__global__ __launch_bounds__(1024) void k_scan(const int* __restrict__ cnt, int* __restrict__ rowptr, int* __restrict__ wp){
  __shared__ int sh[1024];
  __shared__ int carry;
  int tid=threadIdx.x;
  if(tid==0){ carry=0; rowptr[0]=0; }
  __syncthreads();
  for(int base=0;base<NN;base+=1024){
    int i=base+tid;
    int v = (i<NN)? cnt[i]:0;
    sh[tid]=v; __syncthreads();
    for(int off=1;off<1024;off<<=1){
      int t = (tid>=off)? sh[tid-off]:0;
      __syncthreads();
      sh[tid]+=t;
      __syncthreads();
    }
    if(i<NN) rowptr[i+1] = carry + sh[tid];
    __syncthreads();
    if(tid==0) carry += sh[1023];
    __syncthreads();
  }
  for(int i=tid;i<NN;i+=1024) wp[i]=rowptr[i];
}

__global__ void k_scatter(const int* __restrict__ src, const int* __restrict__ dst, const float* __restrict__ wnorm,
                          int* __restrict__ wp, int2* __restrict__ pack){
  int e = blockIdx.x*256+threadIdx.x;
  if(e<EE){
    int d=dst[e];
    int pos = atomicAdd(&wp[d],1);
    pack[pos] = make_int2(src[e], __float_as_int(wnorm[e]));
  }
}

__global__ void k_wreorg(const float* __restrict__ Wx1,const float* __restrict__ bx1,
                         const float* __restrict__ Wh1,const float* __restrict__ bh1,const float* __restrict__ b1,
                         const float* __restrict__ Wx2,const float* __restrict__ bx2,
                         const float* __restrict__ Wh2,const float* __restrict__ bh2,const float* __restrict__ b2g,
                         float* __restrict__ Wc1,float* __restrict__ Wc2,
                         float* __restrict__ Bc1,float* __restrict__ Bc2){
  int idx = blockIdx.x*256+threadIdx.x;
  if(idx < 320*128){
    int r=idx>>7, c=idx&127;
    int g=c>>5, j=c&31;
    float v;
    if(r<160){ int k=r>>5, i=r&31; v=Wx1[((g*5+k)*32+i)*32+j]; }
    else { int rr=r-160; int k=rr>>5,i=rr&31; v=Wh1[((g*5+k)*32+i)*32+j]; }
    Wc1[idx]=v;
  }
  if(idx < 240*64){
    int r=idx>>6, c=idx&63;
    int g=c>>4, j=c&15;
    float v;
    if(r<160){ int k=r>>5,i=r&31; v=Wx2[((g*5+k)*32+i)*16+j]; }
    else { int rr=r-160; int k=rr>>4,i=rr&15; v=Wh2[((g*5+k)*16+i)*16+j]; }
    Wc2[idx]=v;
  }
  if(idx<128){ int g=idx>>5,j=idx&31; Bc1[idx]=bx1[g*32+j]+bh1[g*32+j]+b1[g*32+j]; }
  if(idx<64){ int g=idx>>4,j=idx&15; Bc2[idx]=bx2[g*16+j]+bh2[g*16+j]+b2g[g*16+j]; }
}

// ---------- per-timestep ----------
__global__ void k_init1(const float* __restrict__ xt, const float* __restrict__ h1, float* __restrict__ Z1){
  int idx=blockIdx.x*256+threadIdx.x;
  if(idx<NN*32){
    int n=idx>>5, i=idx&31;
    Z1[n*320+i] = xt[idx];
    Z1[n*320+160+i] = h1[idx];
  }
}

// one wave per node; lanes 0..nA-1 = chain A channels, nA..nA+nB-1 = chain B
__global__ void k_spmm(const int* __restrict__ rowptr, const int2* __restrict__ pack, float* __restrict__ Z,
                       int stride, int nA, int nB,
                       int cinA,int coutA,int cppA,int cinB,int coutB,int cppB,
                       float alpha,float beta){
  int wid = (blockIdx.x*blockDim.x+threadIdx.x)>>6;
  int lane = threadIdx.x&63;
  if(wid>=NN) return;
  int cin=0,cout=0,cpp=0; bool act;
  if(lane<nA){ cin=cinA+lane; cout=coutA+lane; cpp=cppA+lane; act=true; }
  else if(lane<nA+nB){ int l=lane-nA; cin=cinB+l; cout=coutB+l; cpp=cppB+l; act=true; }
  else act=false;
  int e0=rowptr[wid], e1=rowptr[wid+1];
  float acc=0.f;
  for(int e=e0;e<e1;e++){
    int2 p = pack[e];
    if(act) acc += __int_as_float(p.y) * Z[(size_t)p.x*stride + cin];
  }
  if(act){
    float v;
    if(beta==0.f) v = -alpha*acc;
    else          v = -alpha*acc + beta*Z[(size_t)wid*stride+cpp];
    Z[(size_t)wid*stride+cout] = v;
  }
}

// G1 = Z1[10000x320] @ Wc1[320x128], fused LSTM update for layer 1
__global__ __launch_bounds__(256) void k_gemm1(const float* __restrict__ Z1, const float* __restrict__ W,
        const float* __restrict__ Bc, const float* __restrict__ wc1,
        float* __restrict__ h1, float* __restrict__ c1, const float* __restrict__ h2, float* __restrict__ Z2){
  __shared__ float As[32][33];
  __shared__ float Bs[32][128];
  int tid=threadIdx.x;
  int tx=tid&31, ty=tid>>5;     // cols: tx+32q (q = gate), rows: ty*4+rr
  int row0=blockIdx.x*32;
  float acc[4][4];
  #pragma unroll
  for(int r=0;r<4;r++){
    #pragma unroll
    for(int q=0;q<4;q++) acc[r][q]=0.f;
  }
  for(int kb=0;kb<320;kb+=32){
    #pragma unroll
    for(int l=0;l<4;l++){
      int idx=tid+l*256;
      int r=idx>>5, kk=idx&31;
      int gr=row0+r;
      As[r][kk] = (gr<NN)? Z1[(size_t)gr*320 + kb+kk] : 0.f;
    }
    #pragma unroll
    for(int l=0;l<16;l++){
      int idx=tid+l*256;
      int r=idx>>7, c=idx&127;
      Bs[r][c] = W[(kb+r)*128 + c];
    }
    __syncthreads();
    #pragma unroll
    for(int kk=0;kk<32;kk++){
      float a[4], bb[4];
      #pragma unroll
      for(int r=0;r<4;r++) a[r]=As[ty*4+r][kk];
      #pragma unroll
      for(int q=0;q<4;q++) bb[q]=Bs[kk][tx+32*q];
      #pragma unroll
      for(int r=0;r<4;r++){
        #pragma unroll
        for(int q=0;q<4;q++) acc[r][q] += a[r]*bb[q];
      }
    }
    __syncthreads();
  }
  float w0=wc1[tx], w1=wc1[32+tx], w2=wc1[64+tx];
  float bi=Bc[tx], bfv=Bc[32+tx], bc=Bc[64+tx], bo=Bc[96+tx];
  #pragma unroll
  for(int rr=0;rr<4;rr++){
    int row=row0+ty*4+rr;
    if(row<NN){
      float c=c1[row*32+tx];
      float I =sigmf(acc[rr][0]+bi + w0*c);
      float Fg=sigmf(acc[rr][1]+bfv + w1*c);
      float Ct=tanhf(acc[rr][2]+bc);
      float Cn=Fg*c + I*Ct;
      float O =sigmf(acc[rr][3]+bo + w2*Cn);
      float h =O*tanhf(Cn);
      c1[row*32+tx]=Cn; h1[row*32+tx]=h;
      Z2[(size_t)row*240+tx]=h;                       // layer-2 X-chain T0
      if(tx<16) Z2[(size_t)row*240+160+tx]=h2[row*16+tx]; // layer-2 H-chain T0 (prev h2)
    }
  }
}

// G2 = Z2[10000x240] @ Wc2[240x64], fused LSTM update for layer 2
__global__ __launch_bounds__(256) void k_gemm2(const float* __restrict__ Z2, const float* __restrict__ W,
        const float* __restrict__ Bc, const float* __restrict__ wc2,
        float* __restrict__ h2, float* __restrict__ c2){
  __shared__ float As[32][33];
  __shared__ float Bs[32][64];
  int tid=threadIdx.x;
  int tx=tid&15, ty=tid>>4;   // cols: tx+16q (q = gate), rows ty*2+rr
  int row0=blockIdx.x*32;
  float acc[2][4];
  #pragma unroll
  for(int r=0;r<2;r++){
    #pragma unroll
    for(int q=0;q<4;q++) acc[r][q]=0.f;
  }
  for(int kb=0;kb<240;kb+=32){
    #pragma unroll
    for(int l=0;l<4;l++){
      int idx=tid+l*256; int r=idx>>5, kk=idx&31; int gr=row0+r;
      As[r][kk] = (gr<NN && (kb+kk)<240)? Z2[(size_t)gr*240+kb+kk] : 0.f;
    }
    #pragma unroll
    for(int l=0;l<8;l++){
      int idx=tid+l*256; int r=idx>>6, c=idx&63;
      Bs[r][c] = ((kb+r)<240)? W[(kb+r)*64+c] : 0.f;
    }
    __syncthreads();
    #pragma unroll
    for(int kk=0;kk<32;kk++){
      float a0=As[ty*2+0][kk], a1=As[ty*2+1][kk];
      float b0=Bs[kk][tx], b1=Bs[kk][tx+16], b2v=Bs[kk][tx+32], b3=Bs[kk][tx+48];
      acc[0][0]+=a0*b0; acc[0][1]+=a0*b1; acc[0][2]+=a0*b2v; acc[0][3]+=a0*b3;
      acc[1][0]+=a1*b0; acc[1][1]+=a1*b1; acc[1][2]+=a1*b2v; acc[1][3]+=a1*b3;
    }
    __syncthreads();
  }
  float w0=wc2[tx], w1=wc2[16+tx], w2=wc2[32+tx];
  float bi=Bc[tx], bfv=Bc[16+tx], bc=Bc[32+tx], bo=Bc[48+tx];
  #pragma unroll
  for(int rr=0;rr<2;rr++){
    int row=row0+ty*2+rr;
    if(row<NN){
      float c=c2[row*16+tx];
      float I =sigmf(acc[rr][0]+bi+w0*c);
      float Fg=sigmf(acc[rr][1]+bfv+w1*c);
      float Ct=tanhf(acc[rr][2]+bc);
      float Cn=Fg*c+I*Ct;
      float O =sigmf(acc[rr][3]+bo+w2*Cn);
      float h =O*tanhf(Cn);
      c2[row*16+tx]=Cn; h2[row*16+tx]=h;
    }
  }
}

// ---------- readout ----------
__global__ void k_pool(const float* __restrict__ h2, const int* __restrict__ batch, float* __restrict__ u){
  int idx=blockIdx.x*256+threadIdx.x;
  if(idx<NN*16){
    int n=idx>>4, j=idx&15;
    atomicAdd(&u[batch[n]*16+j], h2[idx]);
  }
}

__global__ void k_final(const float* __restrict__ u, const float* __restrict__ lw, const float* __restrict__ lb,
                        float* __restrict__ out){
  int g=threadIdx.x;
  if(g<NG){
    float s=lb[0];
    #pragma unroll
    for(int j=0;j<16;j++) s += u[g*16+j]*lw[j];
    out[g]=s;
  }
}

extern "C" void kernel_launch(void* const* d_in, const int* in_sizes, int n_in,
                              void* d_out, int out_size, void* d_ws, size_t ws_size,
                              hipStream_t stream){
  const float* x   = (const float*)d_in[0];
  const int*   ei  = (const int*)d_in[1];
  const float* ea  = (const float*)d_in[2];
  const int*   bat = (const int*)d_in[3];
  const float* Wx1=(const float*)d_in[4];  const float* bx1=(const float*)d_in[5];
  const float* Wh1=(const float*)d_in[6];  const float* bh1=(const float*)d_in[7];
  const float* wc1=(const float*)d_in[8];  const float* b1 =(const float*)d_in[9];
  const float* Wx2=(const float*)d_in[10]; const float* bx2=(const float*)d_in[11];
  const float* Wh2=(const float*)d_in[12]; const float* bh2=(const float*)d_in[13];
  const float* wc2=(const float*)d_in[14]; const float* b2 =(const float*)d_in[15];
  const float* lw =(const float*)d_in[16]; const float* lb =(const float*)d_in[17];
  const int* src = ei; const int* dst = ei+EE;

  float* ws = (float*)d_ws;
  size_t off=0;
  auto alloc=[&](size_t n)->float*{ float* p=ws+off; off+=(n+15)&~(size_t)15; return p; };
  float* deg=alloc(NN);
  float* h1=alloc(NN*32); float* c1=alloc(NN*32);
  float* h2=alloc(NN*16); float* c2=alloc(NN*16);
  float* u =alloc(NG*16);
  int*   cnt=(int*)alloc(NN);
  size_t zeroEnd=off;
  float* dis=alloc(NN);
  float* wnorm=alloc(EE);
  int*   rowptr=(int*)alloc(NN+1);
  int*   wp=(int*)alloc(NN);
  int2*  pack=(int2*)alloc((size_t)EE*2);
  float* Wc1=alloc(320*128); float* Wc2=alloc(240*64);
  float* Bc1=alloc(128);     float* Bc2=alloc(64);
  float* Z1=alloc((size_t)NN*320); float* Z2=alloc((size_t)NN*240);
  (void)ws_size; (void)in_sizes; (void)n_in; (void)out_size;

  hipMemsetAsync(d_ws, 0, zeroEnd*sizeof(float), stream);
  k_deg    <<<1250,256,0,stream>>>(src,ea,deg);
  k_dis    <<<40,256,0,stream>>>(deg,dis);
  k_wnorm  <<<1250,256,0,stream>>>(src,dst,ea,dis,wnorm,cnt);
  k_scan   <<<1,1024,0,stream>>>(cnt,rowptr,wp);
  k_scatter<<<1250,256,0,stream>>>(src,dst,wnorm,wp,pack);
  k_wreorg <<<160,256,0,stream>>>(Wx1,bx1,Wh1,bh1,b1,Wx2,bx2,Wh2,bh2,b2,Wc1,Wc2,Bc1,Bc2);

  for(int t=0;t<TT;t++){
    k_init1<<<1250,256,0,stream>>>(x + (size_t)t*NN*32, h1, Z1);
    for(int k=1;k<5;k++){
      float alpha = (k==1)?1.f:2.f, beta = (k==1)?0.f:-1.f;
      k_spmm<<<2500,256,0,stream>>>(rowptr,pack,Z1,320,32,32,
          (k-1)*32, k*32, (k-2)*32,
          160+(k-1)*32, 160+k*32, 160+(k-2)*32, alpha,beta);
    }
    k_gemm1<<<313,256,0,stream>>>(Z1,Wc1,Bc1,wc1,h1,c1,h2,Z2);
    for(int k=1;k<5;k++){
      float alpha = (k==1)?1.f:2.f, beta = (k==1)?0.f:-1.f;
      k_spmm<<<2500,256,0,stream>>>(rowptr,pack,Z2,240,32,16,
          (k-1)*32, k*32, (k-2)*32,
          160+(k-1)*16, 160+k*16, 160+(k-2)*16, alpha,beta);
    }
    k_gemm2<<<313,256,0,stream>>>(Z2,Wc2,Bc2,wc2,h2,c2);
  }
  k_pool <<<625,256,0,stream>>>(h2,bat,u);
  k_final<<<1,64,0,stream>>>(u,lw,lb,(float*)d_out);
}

// Round 3
// 1685.531 us; speedup vs baseline: 1.7785x; 1.7785x over previous
//
#include <hip/hip_runtime.h>
#include <hip/hip_bf16.h>

#define TT 8
#define NN 10000
#define EE 320000
#define NG 64

__device__ __forceinline__ float sigmf(float x){ return 1.f/(1.f+expf(-x)); }

// ---------- setup ----------
__global__ void k_deg(const int* __restrict__ src, const float* __restrict__ ea, float* __restrict__ deg){
  int e = blockIdx.x*256 + threadIdx.x;
  if(e<EE) atomicAdd(&deg[src[e]], ea[e]);
}

__global__ void k_dis(const float* __restrict__ deg, float* __restrict__ dis){
  int n = blockIdx.x*256+threadIdx.x;
  if(n<NN){ float d=deg[n]; dis[n] = d>0.f ? rsqrtf(d) : 0.f; }
}

__global__ void k_wnorm(const int* __restrict__ src, const int* __restrict__ dst, const float* __restrict__ ea,
                        const float* __restrict__ dis, float* __restrict__ wnorm, int* __restrict__ cnt){
  int e = blockIdx.x*256+threadIdx.x;
  if(e<EE){
    int s=src[e], d=dst[e];
    wnorm[e] = dis[s]*ea[e]*dis[d];
    atomicAdd(&cnt[d],1);
  }
}

__global__ __launch_bounds__(1024) void k_scan(const int* __restrict__ cnt, int* __restrict__ rowptr, int* __restrict__ wp){
  __shared__ int sh[1024];
  __shared__ int carry;
  int tid=threadIdx.x;
  if(tid==0){ carry=0; rowptr[0]=0; }
  __syncthreads();
  for(int base=0;base<NN;base+=1024){
    int i=base+tid;
    int v = (i<NN)? cnt[i]:0;
    sh[tid]=v; __syncthreads();
    for(int off=1;off<1024;off<<=1){
      int t = (tid>=off)? sh[tid-off]:0;
      __syncthreads();
      sh[tid]+=t;
      __syncthreads();
    }
    if(i<NN) rowptr[i+1] = carry + sh[tid];
    __syncthreads();
    if(tid==0) carry += sh[1023];
    __syncthreads();
  }
  for(int i=tid;i<NN;i+=1024) wp[i]=rowptr[i];
}

__global__ void k_scatter(const int* __restrict__ src, const int* __restrict__ dst, const float* __restrict__ wnorm,
                          int* __restrict__ wp, int2* __restrict__ pack){
  int e = blockIdx.x*256+threadIdx.x;
  if(e<EE){
    int d=dst[e];
    int pos = atomicAdd(&wp[d],1);
    pack[pos] = make_int2(src[e], __float_as_int(wnorm[e]));
  }
}

__global__ void k_wreorg(const float* __restrict__ Wx1,const float* __restrict__ bx1,
                         const float* __restrict__ Wh1,const float* __restrict__ bh1,const float* __restrict__ b1,
                         const float* __restrict__ Wx2,const float* __restrict__ bx2,
                         const float* __restrict__ Wh2,const float* __restrict__ bh2,const float* __restrict__ b2g,
                         float* __restrict__ Wc1,float* __restrict__ Wc2,
                         float* __restrict__ Bc1,float* __restrict__ Bc2){
  int idx = blockIdx.x*256+threadIdx.x;
  if(idx < 320*128){
    int r=idx>>7, c=idx&127;
    int g=c>>5, j=c&31;
    float v;
    if(r<160){ int k=r>>5, i=r&31; v=Wx1[((g*5+k)*32+i)*32+j]; }
    else { int rr=r-160; int k=rr>>5,i=rr&31; v=Wh1[((g*5+k)*32+i)*32+j]; }
    Wc1[idx]=v;
  }
  if(idx < 240*64){
    int r=idx>>6, c=idx&63;
    int g=c>>4, j=c&15;
    float v;
    if(r<160){ int k=r>>5,i=r&31; v=Wx2[((g*5+k)*32+i)*16+j]; }
    else { int rr=r-160; int k=rr>>4,i=rr&15; v=Wh2[((g*5+k)*16+i)*16+j]; }
    Wc2[idx]=v;
  }
  if(idx<128){ int g=idx>>5,j=idx&31; Bc1[idx]=bx1[g*32+j]+bh1[g*32+j]+b1[g*32+j]; }
  if(idx<64){ int g=idx>>4,j=idx&15; Bc2[idx]=bx2[g*16+j]+bh2[g*16+j]+b2g[g*16+j]; }
}

// ---------- per-timestep ----------
// x-part only; H-T0 slot of Z1 is maintained by k_gemm1's epilogue (zeros at t=0 via memset)
__global__ void k_init1(const float* __restrict__ xt, float* __restrict__ Z1){
  int idx=blockIdx.x*256+threadIdx.x;
  if(idx<NN*8){
    int n=idx>>3, c=idx&7;
    float4 v = ((const float4*)xt)[idx];
    *(float4*)&Z1[(size_t)n*320 + c*4] = v;
  }
}

// one wave per node; lanes 0..nA-1 = chain A channels, nA..nA+nB-1 = chain B
// edge loop unrolled x8: 8 pack loads + 8 gathers in flight per group
__global__ void k_spmm(const int* __restrict__ rowptr, const int2* __restrict__ pack, float* __restrict__ Z,
                       int stride, int nA, int nB,
                       int cinA,int coutA,int cppA,int cinB,int coutB,int cppB,
                       float alpha,float beta){
  int wid = (blockIdx.x*blockDim.x+threadIdx.x)>>6;
  int lane = threadIdx.x&63;
  if(wid>=NN) return;
  int cin=0,cout=0,cpp=0; bool act;
  if(lane<nA){ cin=cinA+lane; cout=coutA+lane; cpp=cppA+lane; act=true; }
  else if(lane<nA+nB){ int l=lane-nA; cin=cinB+l; cout=coutB+l; cpp=cppB+l; act=true; }
  else act=false;
  int e0=rowptr[wid], e1=rowptr[wid+1];
  float acc=0.f;
  int e=e0;
  for(; e+8<=e1; e+=8){
    int2 p0=pack[e+0],p1=pack[e+1],p2=pack[e+2],p3=pack[e+3];
    int2 p4=pack[e+4],p5=pack[e+5],p6=pack[e+6],p7=pack[e+7];
    if(act){
      float z0=Z[(size_t)p0.x*stride+cin];
      float z1=Z[(size_t)p1.x*stride+cin];
      float z2=Z[(size_t)p2.x*stride+cin];
      float z3=Z[(size_t)p3.x*stride+cin];
      float z4=Z[(size_t)p4.x*stride+cin];
      float z5=Z[(size_t)p5.x*stride+cin];
      float z6=Z[(size_t)p6.x*stride+cin];
      float z7=Z[(size_t)p7.x*stride+cin];
      acc += __int_as_float(p0.y)*z0; acc += __int_as_float(p1.y)*z1;
      acc += __int_as_float(p2.y)*z2; acc += __int_as_float(p3.y)*z3;
      acc += __int_as_float(p4.y)*z4; acc += __int_as_float(p5.y)*z5;
      acc += __int_as_float(p6.y)*z6; acc += __int_as_float(p7.y)*z7;
    }
  }
  for(; e<e1; ++e){
    int2 p=pack[e];
    if(act) acc += __int_as_float(p.y)*Z[(size_t)p.x*stride+cin];
  }
  if(act){
    float v = -alpha*acc;
    if(beta!=0.f) v += beta*Z[(size_t)wid*stride+cpp];
    Z[(size_t)wid*stride+cout] = v;
  }
}

// G1 = Z1[10000x320] @ Wc1[320x128], fused LSTM layer-1 update.
// Writes: c1, Z1 H-T0 slot (next step), Z2 X-T0 slot (this step).
__global__ __launch_bounds__(256) void k_gemm1(float* Z1, const float* __restrict__ W,
        const float* __restrict__ Bc, const float* __restrict__ wc1,
        float* __restrict__ c1, float* __restrict__ Z2){
  __shared__ float As[32][328];
  __shared__ float Bs[32][132];
  int tid=threadIdx.x;
  int tx=tid&31, ty=tid>>5;     // cols: tx+32q (q = gate), rows: ty*4+rr
  int row0=blockIdx.x*32;
  // stage full A tile (32x320), 10 independent float4 loads per thread
  {
    int r=tid&31, c4=tid>>5;
    int gr=row0+r;
    const float4* zr = (const float4*)(Z1 + (size_t)gr*320);
    #pragma unroll
    for(int j=0;j<10;j++){
      int k4=c4+j*8;
      float4 v = (gr<NN)? zr[k4] : make_float4(0.f,0.f,0.f,0.f);
      *(float4*)&As[r][k4*4]=v;
    }
  }
  // W slab double-buffer through registers
  float4 wreg[4];
  #pragma unroll
  for(int j=0;j<4;j++) wreg[j]=((const float4*)W)[tid+j*256];
  float acc[4][4]={};
  __syncthreads();
  for(int kb=0;kb<320;kb+=32){
    #pragma unroll
    for(int j=0;j<4;j++){
      int idx=tid+j*256;
      int k=idx>>5, c0=(idx&31)*4;
      *(float4*)&Bs[k][c0]=wreg[j];
    }
    __syncthreads();
    if(kb+32<320){
      #pragma unroll
      for(int j=0;j<4;j++) wreg[j]=((const float4*)W)[(kb+32)*32 + tid+j*256];
    }
    #pragma unroll
    for(int kq=0;kq<8;kq++){
      float a[4][4];
      #pragma unroll
      for(int r=0;r<4;r++){
        float4 t = *(const float4*)&As[ty*4+r][kb+kq*4];
        a[r][0]=t.x; a[r][1]=t.y; a[r][2]=t.z; a[r][3]=t.w;
      }
      #pragma unroll
      for(int sub=0;sub<4;sub++){
        int kk=kq*4+sub;
        #pragma unroll
        for(int q=0;q<4;q++){
          float bq=Bs[kk][tx+32*q];
          #pragma unroll
          for(int r=0;r<4;r++) acc[r][q]+=a[r][sub]*bq;
        }
      }
    }
    __syncthreads();
  }
  float w0=wc1[tx], w1=wc1[32+tx], w2=wc1[64+tx];
  float bi=Bc[tx], bfv=Bc[32+tx], bc=Bc[64+tx], bo=Bc[96+tx];
  #pragma unroll
  for(int rr=0;rr<4;rr++){
    int row=row0+ty*4+rr;
    if(row<NN){
      float c=c1[row*32+tx];
      float I =sigmf(acc[rr][0]+bi + w0*c);
      float Fg=sigmf(acc[rr][1]+bfv + w1*c);
      float Ct=tanhf(acc[rr][2]+bc);
      float Cn=Fg*c + I*Ct;
      float O =sigmf(acc[rr][3]+bo + w2*Cn);
      float h =O*tanhf(Cn);
      c1[row*32+tx]=Cn;
      Z1[(size_t)row*320+160+tx]=h;   // next-step layer-1 H-chain T0
      Z2[(size_t)row*240+tx]=h;       // this-step layer-2 X-chain T0
    }
  }
}

// G2 = Z2[10000x240] @ Wc2[240x64], fused LSTM layer-2 update.
// Writes: c2, h2, Z2 H-T0 slot (next step).
__global__ __launch_bounds__(256) void k_gemm2(float* Z2, const float* __restrict__ W,
        const float* __restrict__ Bc, const float* __restrict__ wc2,
        float* __restrict__ c2, float* __restrict__ h2){
  __shared__ float As[32][264];
  __shared__ float Bs[48][68];
  int tid=threadIdx.x;
  int tx=tid&15, ty=tid>>4;   // cols: tx+16q (q = gate), rows ty*2+rr
  int row0=blockIdx.x*32;
  {
    int r=tid&31, c4=tid>>5;
    int gr=row0+r;
    const float4* zr=(const float4*)(Z2 + (size_t)gr*240);
    #pragma unroll
    for(int j=0;j<8;j++){
      int k4=c4+j*8;  // up to float 255; Z2 alloc padded +64 floats
      float4 v=(gr<NN)? zr[k4] : make_float4(0.f,0.f,0.f,0.f);
      *(float4*)&As[r][k4*4]=v;
    }
  }
  float4 wreg[3];
  #pragma unroll
  for(int j=0;j<3;j++) wreg[j]=((const float4*)W)[tid+j*256];
  float acc[2][4]={};
  __syncthreads();
  for(int s=0;s<5;s++){
    int kb=s*48;
    #pragma unroll
    for(int j=0;j<3;j++){
      int idx=tid+j*256;           // 0..767 float4 of slab (48x64)
      int k=idx>>4, c0=(idx&15)*4;
      *(float4*)&Bs[k][c0]=wreg[j];
    }
    __syncthreads();
    if(s<4){
      #pragma unroll
      for(int j=0;j<3;j++) wreg[j]=((const float4*)W)[(s+1)*768 + tid+j*256];
    }
    #pragma unroll
    for(int kq=0;kq<12;kq++){
      float a[2][4];
      #pragma unroll
      for(int r=0;r<2;r++){
        float4 t=*(const float4*)&As[ty*2+r][kb+kq*4];
        a[r][0]=t.x; a[r][1]=t.y; a[r][2]=t.z; a[r][3]=t.w;
      }
      #pragma unroll
      for(int sub=0;sub<4;sub++){
        int kk=kq*4+sub;
        #pragma unroll
        for(int q=0;q<4;q++){
          float bq=Bs[kk][tx+16*q];
          #pragma unroll
          for(int r=0;r<2;r++) acc[r][q]+=a[r][sub]*bq;
        }
      }
    }
    __syncthreads();
  }
  float w0=wc2[tx], w1=wc2[16+tx], w2=wc2[32+tx];
  float bi=Bc[tx], bfv=Bc[16+tx], bc=Bc[32+tx], bo=Bc[48+tx];
  #pragma unroll
  for(int rr=0;rr<2;rr++){
    int row=row0+ty*2+rr;
    if(row<NN){
      float c=c2[row*16+tx];
      float I =sigmf(acc[rr][0]+bi+w0*c);
      float Fg=sigmf(acc[rr][1]+bfv+w1*c);
      float Ct=tanhf(acc[rr][2]+bc);
      float Cn=Fg*c+I*Ct;
      float O =sigmf(acc[rr][3]+bo+w2*Cn);
      float h =O*tanhf(Cn);
      c2[row*16+tx]=Cn; h2[row*16+tx]=h;
      Z2[(size_t)row*240+160+tx]=h;   // next-step layer-2 H-chain T0
    }
  }
}

// ---------- readout ----------
__global__ void k_pool(const float* __restrict__ h2, const int* __restrict__ batch, float* __restrict__ u){
  int idx=blockIdx.x*256+threadIdx.x;
  if(idx<NN*16){
    int n=idx>>4, j=idx&15;
    atomicAdd(&u[batch[n]*16+j], h2[idx]);
  }
}

__global__ void k_final(const float* __restrict__ u, const float* __restrict__ lw, const float* __restrict__ lb,
                        float* __restrict__ out){
  int g=threadIdx.x;
  if(g<NG){
    float s=lb[0];
    #pragma unroll
    for(int j=0;j<16;j++) s += u[g*16+j]*lw[j];
    out[g]=s;
  }
}

extern "C" void kernel_launch(void* const* d_in, const int* in_sizes, int n_in,
                              void* d_out, int out_size, void* d_ws, size_t ws_size,
                              hipStream_t stream){
  const float* x   = (const float*)d_in[0];
  const int*   ei  = (const int*)d_in[1];
  const float* ea  = (const float*)d_in[2];
  const int*   bat = (const int*)d_in[3];
  const float* Wx1=(const float*)d_in[4];  const float* bx1=(const float*)d_in[5];
  const float* Wh1=(const float*)d_in[6];  const float* bh1=(const float*)d_in[7];
  const float* wc1=(const float*)d_in[8];  const float* b1 =(const float*)d_in[9];
  const float* Wx2=(const float*)d_in[10]; const float* bx2=(const float*)d_in[11];
  const float* Wh2=(const float*)d_in[12]; const float* bh2=(const float*)d_in[13];
  const float* wc2=(const float*)d_in[14]; const float* b2 =(const float*)d_in[15];
  const float* lw =(const float*)d_in[16]; const float* lb =(const float*)d_in[17];
  const int* src = ei; const int* dst = ei+EE;

  float* ws = (float*)d_ws;
  size_t off=0;
  auto alloc=[&](size_t n)->float*{ float* p=ws+off; off+=(n+15)&~(size_t)15; return p; };
  // zeroed region (memset below): deg, c1, c2, u, cnt, Z1, Z2
  float* deg=alloc(NN);
  float* c1=alloc((size_t)NN*32);
  float* c2=alloc((size_t)NN*16);
  float* u =alloc(NG*16);
  int*   cnt=(int*)alloc(NN);
  float* Z1=alloc((size_t)NN*320);
  float* Z2=alloc((size_t)NN*240+64);
  size_t zeroEnd=off;
  float* h2=alloc((size_t)NN*16);
  float* dis=alloc(NN);
  float* wnorm=alloc(EE);
  int*   rowptr=(int*)alloc(NN+1);
  int*   wp=(int*)alloc(NN);
  int2*  pack=(int2*)alloc((size_t)EE*2);
  float* Wc1=alloc(320*128); float* Wc2=alloc(240*64);
  float* Bc1=alloc(128);     float* Bc2=alloc(64);
  (void)ws_size; (void)in_sizes; (void)n_in; (void)out_size;

  hipMemsetAsync(d_ws, 0, zeroEnd*sizeof(float), stream);
  k_deg    <<<1250,256,0,stream>>>(src,ea,deg);
  k_dis    <<<40,256,0,stream>>>(deg,dis);
  k_wnorm  <<<1250,256,0,stream>>>(src,dst,ea,dis,wnorm,cnt);
  k_scan   <<<1,1024,0,stream>>>(cnt,rowptr,wp);
  k_scatter<<<1250,256,0,stream>>>(src,dst,wnorm,wp,pack);
  k_wreorg <<<160,256,0,stream>>>(Wx1,bx1,Wh1,bh1,b1,Wx2,bx2,Wh2,bh2,b2,Wc1,Wc2,Bc1,Bc2);

  for(int t=0;t<TT;t++){
    k_init1<<<313,256,0,stream>>>(x + (size_t)t*NN*32, Z1);
    for(int k=1;k<5;k++){
      float alpha = (k==1)?1.f:2.f, beta = (k==1)?0.f:-1.f;
      k_spmm<<<2500,256,0,stream>>>(rowptr,pack,Z1,320,32,32,
          (k-1)*32, k*32, (k-2)*32,
          160+(k-1)*32, 160+k*32, 160+(k-2)*32, alpha,beta);
    }
    k_gemm1<<<313,256,0,stream>>>(Z1,Wc1,Bc1,wc1,c1,Z2);
    for(int k=1;k<5;k++){
      float alpha = (k==1)?1.f:2.f, beta = (k==1)?0.f:-1.f;
      k_spmm<<<2500,256,0,stream>>>(rowptr,pack,Z2,240,32,16,
          (k-1)*32, k*32, (k-2)*32,
          160+(k-1)*16, 160+k*16, 160+(k-2)*16, alpha,beta);
    }
    k_gemm2<<<313,256,0,stream>>>(Z2,Wc2,Bc2,wc2,c2,h2);
  }
  k_pool <<<625,256,0,stream>>>(h2,bat,u);
  k_final<<<1,64,0,stream>>>(u,lw,lb,(float*)d_out);
}

// Round 4
// 1373.026 us; speedup vs baseline: 2.1833x; 1.2276x over previous
//
#include <hip/hip_runtime.h>
#include <hip/hip_bf16.h>

#define TT 8
#define NN 10000
#define EE 320000
#define NG 64

__device__ __forceinline__ float sigmf(float x){ return 1.f/(1.f+expf(-x)); }

// ---------- setup ----------
__global__ void k_deg(const int* __restrict__ src, const float* __restrict__ ea, float* __restrict__ deg){
  int e = blockIdx.x*256 + threadIdx.x;
  if(e<EE) atomicAdd(&deg[src[e]], ea[e]);
}

__global__ void k_dis(const float* __restrict__ deg, float* __restrict__ dis){
  int n = blockIdx.x*256+threadIdx.x;
  if(n<NN){ float d=deg[n]; dis[n] = d>0.f ? rsqrtf(d) : 0.f; }
}

__global__ void k_wnorm(const int* __restrict__ src, const int* __restrict__ dst, const float* __restrict__ ea,
                        const float* __restrict__ dis, float* __restrict__ wnorm, int* __restrict__ cnt){
  int e = blockIdx.x*256+threadIdx.x;
  if(e<EE){
    int s=src[e], d=dst[e];
    wnorm[e] = dis[s]*ea[e]*dis[d];
    atomicAdd(&cnt[d],1);
  }
}

__global__ __launch_bounds__(1024) void k_scan(const int* __restrict__ cnt, int* __restrict__ rowptr, int* __restrict__ wp){
  __shared__ int wsum[16];
  __shared__ int carrysh;
  int tid=threadIdx.x, lane=tid&63, wv=tid>>6;
  if(tid==0){ carrysh=0; rowptr[0]=0; }
  __syncthreads();
  for(int base=0;base<NN;base+=1024){
    int i=base+tid;
    int v=(i<NN)?cnt[i]:0;
    int s=v;
    #pragma unroll
    for(int d=1;d<64;d<<=1){ int t=__shfl_up(s,d,64); if(lane>=d) s+=t; }
    if(lane==63) wsum[wv]=s;
    __syncthreads();
    if(wv==0 && lane<16){
      int t=wsum[lane]; int ss=t;
      #pragma unroll
      for(int d=1;d<16;d<<=1){ int u=__shfl_up(ss,d,64); if(lane>=d) ss+=u; }
      wsum[lane]=ss-t;  // exclusive prefix of wave sums
    }
    __syncthreads();
    int total = carrysh + wsum[wv] + s;   // inclusive scan value
    if(i<NN) rowptr[i+1]=total;
    __syncthreads();
    if(tid==1023) carrysh = total;
    __syncthreads();
  }
  for(int i=tid;i<NN;i+=1024) wp[i]=rowptr[i];
}

__global__ void k_scatter(const int* __restrict__ src, const int* __restrict__ dst, const float* __restrict__ wnorm,
                          int* __restrict__ wp, int2* __restrict__ pack){
  int e = blockIdx.x*256+threadIdx.x;
  if(e<EE){
    int d=dst[e];
    int pos = atomicAdd(&wp[d],1);
    pack[pos] = make_int2(src[e], __float_as_int(wnorm[e]));
  }
}

__global__ void k_wreorg(const float* __restrict__ Wx1,const float* __restrict__ bx1,
                         const float* __restrict__ Wh1,const float* __restrict__ bh1,const float* __restrict__ b1,
                         const float* __restrict__ Wx2,const float* __restrict__ bx2,
                         const float* __restrict__ Wh2,const float* __restrict__ bh2,const float* __restrict__ b2g,
                         float* __restrict__ Wc1,float* __restrict__ Wc2,
                         float* __restrict__ Bc1,float* __restrict__ Bc2){
  int idx = blockIdx.x*256+threadIdx.x;
  if(idx < 320*128){
    int r=idx>>7, c=idx&127;
    int g=c>>5, j=c&31;
    float v;
    if(r<160){ int k=r>>5, i=r&31; v=Wx1[((g*5+k)*32+i)*32+j]; }
    else { int rr=r-160; int k=rr>>5,i=rr&31; v=Wh1[((g*5+k)*32+i)*32+j]; }
    Wc1[idx]=v;
  }
  if(idx < 240*64){
    int r=idx>>6, c=idx&63;
    int g=c>>4, j=c&15;
    float v;
    if(r<160){ int k=r>>5,i=r&31; v=Wx2[((g*5+k)*32+i)*16+j]; }
    else { int rr=r-160; int k=rr>>4,i=rr&15; v=Wh2[((g*5+k)*16+i)*16+j]; }
    Wc2[idx]=v;
  }
  if(idx<128){ int g=idx>>5,j=idx&31; Bc1[idx]=bx1[g*32+j]+bh1[g*32+j]+b1[g*32+j]; }
  if(idx<64){ int g=idx>>4,j=idx&15; Bc2[idx]=bx2[g*16+j]+bh2[g*16+j]+b2g[g*16+j]; }
}

// ---------- per-timestep ----------
// t=0 only: X slot of Z1
__global__ void k_init1(const float* __restrict__ xt, float* __restrict__ Z1){
  int idx=blockIdx.x*256+threadIdx.x;
  if(idx<NN*8){
    int n=idx>>3, c=idx&7;
    float4 v = ((const float4*)xt)[idx];
    *(float4*)&Z1[(size_t)n*320 + c*4] = v;
  }
}

// one wave per node; lanes 0..NA-1 = X chain, NA..NA+NB-1 = H chain
template<int STRIDE,int NA,int NB>
__global__ __launch_bounds__(256) void k_spmm(const int* __restrict__ rowptr, const int2* __restrict__ pack,
                       float* __restrict__ Z,
                       int cinA,int coutA,int cppA,int cinB,int coutB,int cppB,
                       float alpha,float beta){
  int wlocal = __builtin_amdgcn_readfirstlane(threadIdx.x>>6);
  int wid = blockIdx.x*4 + wlocal;
  if(wid>=NN) return;
  int lane = threadIdx.x&63;
  bool act = lane < NA+NB;
  int cin  = lane<NA ? cinA+lane : cinB+(lane-NA);
  int cout = lane<NA ? coutA+lane : coutB+(lane-NA);
  int cpp  = lane<NA ? cppA +lane : cppB+(lane-NA);
  if(!act) cin=0;
  const float* __restrict__ Zc = Z + cin;
  int e0=rowptr[wid], e1=rowptr[wid+1];
  float acc=0.f;
  int e=e0;
  for(; e+16<=e1; e+=16){
    float w[16], z[16];
    #pragma unroll
    for(int j=0;j<16;j++){
      int2 p=pack[e+j];
      w[j]=__int_as_float(p.y);
      z[j]=Zc[(unsigned)p.x*STRIDE];
    }
    #pragma unroll
    for(int j=0;j<16;j++) acc += w[j]*z[j];
  }
  for(; e+4<=e1; e+=4){
    float w[4], z[4];
    #pragma unroll
    for(int j=0;j<4;j++){ int2 p=pack[e+j]; w[j]=__int_as_float(p.y); z[j]=Zc[(unsigned)p.x*STRIDE]; }
    #pragma unroll
    for(int j=0;j<4;j++) acc += w[j]*z[j];
  }
  for(; e<e1; ++e){ int2 p=pack[e]; acc += __int_as_float(p.y)*Zc[(unsigned)p.x*STRIDE]; }
  if(act){
    float v = -alpha*acc;
    if(beta!=0.f) v += beta*Z[(unsigned)wid*STRIDE+cpp];
    Z[(unsigned)wid*STRIDE+cout]=v;
  }
}

// G1 = Z1[10000x320] @ Wc1[320x128], fused LSTM layer-1 update.
// tile 16 rows x 128 cols, 625 blocks x 256 threads; thread: rows {ty, ty+8}, cols tx+32q
__global__ __launch_bounds__(256) void k_gemm1(float* __restrict__ Z1, const float* __restrict__ W,
        const float* __restrict__ Bc, const float* __restrict__ wc1,
        float* __restrict__ c1, float* __restrict__ Z2){
  __shared__ float As[16][324];
  __shared__ float BsT[2][128][34];   // [col][k_local], float2-aligned rows
  int tid=threadIdx.x;
  int tx=tid&31, ty=tid>>5;
  int row0=blockIdx.x*16;
  // A stage: 16 rows x 80 float4, coalesced
  #pragma unroll
  for(int i=0;i<5;i++){
    int idx=tid+i*256;
    int r=idx/80, c4=idx-r*80;
    int gr=row0+r;
    float4 v = (gr<NN)? *(const float4*)&Z1[(size_t)gr*320 + c4*4] : make_float4(0,0,0,0);
    *(float4*)&As[r][c4*4]=v;
  }
  int bc=tid&127, brg=tid>>7;   // col, row-group(0..1)
  // stage slab 0
  #pragma unroll
  for(int i=0;i<4;i++){
    int r0=brg*4+i*8;
    float a=W[(r0+0)*128+bc], b=W[(r0+1)*128+bc], c=W[(r0+2)*128+bc], d=W[(r0+3)*128+bc];
    *(float2*)&BsT[0][bc][r0]  =make_float2(a,b);
    *(float2*)&BsT[0][bc][r0+2]=make_float2(c,d);
  }
  float acc[2][4]={};
  __syncthreads();
  for(int s=0;s<10;s++){
    int kb=s*32;
    float pw[16];
    if(s<9){
      #pragma unroll
      for(int i=0;i<4;i++){
        int r0=brg*4+i*8;
        #pragma unroll
        for(int j=0;j<4;j++) pw[i*4+j]=W[(kb+32+r0+j)*128+bc];
      }
    }
    #pragma unroll
    for(int kq=0;kq<8;kq++){
      float4 a0=*(const float4*)&As[ty][kb+kq*4];
      float4 a1=*(const float4*)&As[ty+8][kb+kq*4];
      #pragma unroll
      for(int q=0;q<4;q++){
        float2 b01=*(const float2*)&BsT[s&1][tx+32*q][kq*4];
        float2 b23=*(const float2*)&BsT[s&1][tx+32*q][kq*4+2];
        acc[0][q]+=a0.x*b01.x; acc[0][q]+=a0.y*b01.y; acc[0][q]+=a0.z*b23.x; acc[0][q]+=a0.w*b23.y;
        acc[1][q]+=a1.x*b01.x; acc[1][q]+=a1.y*b01.y; acc[1][q]+=a1.z*b23.x; acc[1][q]+=a1.w*b23.y;
      }
    }
    if(s<9){
      int b2=(s+1)&1;
      #pragma unroll
      for(int i=0;i<4;i++){
        int r0=brg*4+i*8;
        *(float2*)&BsT[b2][bc][r0]  =make_float2(pw[i*4],pw[i*4+1]);
        *(float2*)&BsT[b2][bc][r0+2]=make_float2(pw[i*4+2],pw[i*4+3]);
      }
    }
    __syncthreads();
  }
  float w0=wc1[tx], w1=wc1[32+tx], w2=wc1[64+tx];
  float bi=Bc[tx], bfv=Bc[32+tx], bcc=Bc[64+tx], bo=Bc[96+tx];
  #pragma unroll
  for(int rr=0;rr<2;rr++){
    int row=row0+ty+rr*8;
    if(row<NN){
      float c=c1[row*32+tx];
      float I =sigmf(acc[rr][0]+bi + w0*c);
      float Fg=sigmf(acc[rr][1]+bfv + w1*c);
      float Ct=tanhf(acc[rr][2]+bcc);
      float Cn=Fg*c + I*Ct;
      float O =sigmf(acc[rr][3]+bo + w2*Cn);
      float h =O*tanhf(Cn);
      c1[row*32+tx]=Cn;
      Z1[(size_t)row*320+160+tx]=h;   // next-step layer-1 H-chain T0
      Z2[(size_t)row*240+tx]=h;       // this-step layer-2 X-chain T0
    }
  }
}

// G2 = Z2[10000x240] @ Wc2[240x64], fused LSTM layer-2 update + x[t+1] copy.
// tile 16 rows x 64 cols, 625 blocks x 256 threads; thread: row ty, cols tx+16q
__global__ __launch_bounds__(256) void k_gemm2(float* __restrict__ Z2, const float* __restrict__ W,
        const float* __restrict__ Bc, const float* __restrict__ wc2,
        float* __restrict__ c2, float* __restrict__ h2,
        const float* __restrict__ xn, float* __restrict__ Z1){
  __shared__ float As[16][244];
  __shared__ float BsT[2][64][50];
  int tid=threadIdx.x;
  int tx=tid&15, ty=tid>>4;
  int row0=blockIdx.x*16;
  #pragma unroll
  for(int i=0;i<4;i++){
    int idx=tid+i*256;
    if(idx<960){
      int r=idx/60, c4=idx-r*60;
      int gr=row0+r;
      float4 v=(gr<NN)? *(const float4*)&Z2[(size_t)gr*240+c4*4] : make_float4(0,0,0,0);
      *(float4*)&As[r][c4*4]=v;
    }
  }
  int bc=tid&63, brg=tid>>6;   // col, row-group(0..3)
  #pragma unroll
  for(int i=0;i<3;i++){
    int r0=brg*4+i*16;
    float a=W[(r0+0)*64+bc], b=W[(r0+1)*64+bc], c=W[(r0+2)*64+bc], d=W[(r0+3)*64+bc];
    *(float2*)&BsT[0][bc][r0]  =make_float2(a,b);
    *(float2*)&BsT[0][bc][r0+2]=make_float2(c,d);
  }
  float acc[4]={};
  __syncthreads();
  for(int s=0;s<5;s++){
    int kb=s*48;
    float pw[12];
    if(s<4){
      #pragma unroll
      for(int i=0;i<3;i++){
        int r0=brg*4+i*16;
        #pragma unroll
        for(int j=0;j<4;j++) pw[i*4+j]=W[(kb+48+r0+j)*64+bc];
      }
    }
    #pragma unroll
    for(int kq=0;kq<12;kq++){
      float4 a=*(const float4*)&As[ty][kb+kq*4];
      #pragma unroll
      for(int q=0;q<4;q++){
        float2 b01=*(const float2*)&BsT[s&1][tx+16*q][kq*4];
        float2 b23=*(const float2*)&BsT[s&1][tx+16*q][kq*4+2];
        acc[q]+=a.x*b01.x; acc[q]+=a.y*b01.y; acc[q]+=a.z*b23.x; acc[q]+=a.w*b23.y;
      }
    }
    if(s<4){
      int b2=(s+1)&1;
      #pragma unroll
      for(int i=0;i<3;i++){
        int r0=brg*4+i*16;
        *(float2*)&BsT[b2][bc][r0]  =make_float2(pw[i*4],pw[i*4+1]);
        *(float2*)&BsT[b2][bc][r0+2]=make_float2(pw[i*4+2],pw[i*4+3]);
      }
    }
    __syncthreads();
  }
  float w0=wc2[tx], w1=wc2[16+tx], w2=wc2[32+tx];
  float bi=Bc[tx], bfv=Bc[16+tx], bcc=Bc[32+tx], bo=Bc[48+tx];
  int row=row0+ty;
  if(row<NN){
    float c=c2[row*16+tx];
    float I =sigmf(acc[0]+bi+w0*c);
    float Fg=sigmf(acc[1]+bfv+w1*c);
    float Ct=tanhf(acc[2]+bcc);
    float Cn=Fg*c+I*Ct;
    float O =sigmf(acc[3]+bo+w2*Cn);
    float h =O*tanhf(Cn);
    c2[row*16+tx]=Cn; h2[row*16+tx]=h;
    Z2[(size_t)row*240+160+tx]=h;     // next-step layer-2 H-chain T0
    if(xn){
      float2 xv=*(const float2*)&xn[(size_t)row*32+tx*2];
      *(float2*)&Z1[(size_t)row*320+tx*2]=xv;   // next-step layer-1 X-chain T0
    }
  }
}

// ---------- readout ----------
__global__ void k_pool(const float* __restrict__ h2, const int* __restrict__ batch, float* __restrict__ u){
  int idx=blockIdx.x*256+threadIdx.x;
  if(idx<NN*16){
    int n=idx>>4, j=idx&15;
    atomicAdd(&u[batch[n]*16+j], h2[idx]);
  }
}

__global__ void k_final(const float* __restrict__ u, const float* __restrict__ lw, const float* __restrict__ lb,
                        float* __restrict__ out){
  int g=threadIdx.x;
  if(g<NG){
    float s=lb[0];
    #pragma unroll
    for(int j=0;j<16;j++) s += u[g*16+j]*lw[j];
    out[g]=s;
  }
}

extern "C" void kernel_launch(void* const* d_in, const int* in_sizes, int n_in,
                              void* d_out, int out_size, void* d_ws, size_t ws_size,
                              hipStream_t stream){
  const float* x   = (const float*)d_in[0];
  const int*   ei  = (const int*)d_in[1];
  const float* ea  = (const float*)d_in[2];
  const int*   bat = (const int*)d_in[3];
  const float* Wx1=(const float*)d_in[4];  const float* bx1=(const float*)d_in[5];
  const float* Wh1=(const float*)d_in[6];  const float* bh1=(const float*)d_in[7];
  const float* wc1=(const float*)d_in[8];  const float* b1 =(const float*)d_in[9];
  const float* Wx2=(const float*)d_in[10]; const float* bx2=(const float*)d_in[11];
  const float* Wh2=(const float*)d_in[12]; const float* bh2=(const float*)d_in[13];
  const float* wc2=(const float*)d_in[14]; const float* b2 =(const float*)d_in[15];
  const float* lw =(const float*)d_in[16]; const float* lb =(const float*)d_in[17];
  const int* src = ei; const int* dst = ei+EE;

  float* ws = (float*)d_ws;
  size_t off=0;
  auto alloc=[&](size_t n)->float*{ float* p=ws+off; off+=(n+15)&~(size_t)15; return p; };
  // zeroed region: deg, c1, c2, u, cnt, Z1, Z2
  float* deg=alloc(NN);
  float* c1=alloc((size_t)NN*32);
  float* c2=alloc((size_t)NN*16);
  float* u =alloc(NG*16);
  int*   cnt=(int*)alloc(NN);
  float* Z1=alloc((size_t)NN*320);
  float* Z2=alloc((size_t)NN*240+64);
  size_t zeroEnd=off;
  float* h2=alloc((size_t)NN*16);
  float* dis=alloc(NN);
  float* wnorm=alloc(EE);
  int*   rowptr=(int*)alloc(NN+1);
  int*   wp=(int*)alloc(NN);
  int2*  pack=(int2*)alloc((size_t)EE*2);
  float* Wc1=alloc(320*128); float* Wc2=alloc(240*64);
  float* Bc1=alloc(128);     float* Bc2=alloc(64);
  (void)ws_size; (void)in_sizes; (void)n_in; (void)out_size;

  hipMemsetAsync(d_ws, 0, zeroEnd*sizeof(float), stream);
  k_deg    <<<1250,256,0,stream>>>(src,ea,deg);
  k_dis    <<<40,256,0,stream>>>(deg,dis);
  k_wnorm  <<<1250,256,0,stream>>>(src,dst,ea,dis,wnorm,cnt);
  k_scan   <<<1,1024,0,stream>>>(cnt,rowptr,wp);
  k_scatter<<<1250,256,0,stream>>>(src,dst,wnorm,wp,pack);
  k_wreorg <<<160,256,0,stream>>>(Wx1,bx1,Wh1,bh1,b1,Wx2,bx2,Wh2,bh2,b2,Wc1,Wc2,Bc1,Bc2);

  k_init1<<<313,256,0,stream>>>(x, Z1);
  for(int t=0;t<TT;t++){
    for(int k=1;k<5;k++){
      float alpha = (k==1)?1.f:2.f, beta = (k==1)?0.f:-1.f;
      k_spmm<320,32,32><<<2500,256,0,stream>>>(rowptr,pack,Z1,
          (k-1)*32, k*32, (k-2)*32,
          160+(k-1)*32, 160+k*32, 160+(k-2)*32, alpha,beta);
    }
    k_gemm1<<<625,256,0,stream>>>(Z1,Wc1,Bc1,wc1,c1,Z2);
    for(int k=1;k<5;k++){
      float alpha = (k==1)?1.f:2.f, beta = (k==1)?0.f:-1.f;
      k_spmm<240,32,16><<<2500,256,0,stream>>>(rowptr,pack,Z2,
          (k-1)*32, k*32, (k-2)*32,
          160+(k-1)*16, 160+k*16, 160+(k-2)*16, alpha,beta);
    }
    k_gemm2<<<625,256,0,stream>>>(Z2,Wc2,Bc2,wc2,c2,h2,
          (t<TT-1)? x+(size_t)(t+1)*NN*32 : nullptr, Z1);
  }
  k_pool <<<625,256,0,stream>>>(h2,bat,u);
  k_final<<<1,64,0,stream>>>(u,lw,lb,(float*)d_out);
}

// Round 5
// 1301.938 us; speedup vs baseline: 2.3025x; 1.0546x over previous
//
#include <hip/hip_runtime.h>
#include <hip/hip_bf16.h>

#define TT 8
#define NN 10000
#define EE 320000
#define NG 64

typedef short v8s __attribute__((ext_vector_type(8)));
typedef float v4f __attribute__((ext_vector_type(4)));

__device__ __forceinline__ float sigmf(float x){ return 1.f/(1.f+expf(-x)); }
__device__ __forceinline__ short f2bf(float f){
  unsigned u=__float_as_uint(f);
  unsigned r=(u + 0x7FFFu + ((u>>16)&1u))>>16;
  return (short)r;
}
__device__ __forceinline__ float bf2f(short s){
  return __uint_as_float(((unsigned)(unsigned short)s)<<16);
}

// ---------- setup ----------
__global__ void k_deg(const int* __restrict__ src, const float* __restrict__ ea, float* __restrict__ deg){
  int e = blockIdx.x*256 + threadIdx.x;
  if(e<EE) atomicAdd(&deg[src[e]], ea[e]);
}

__global__ void k_dis(const float* __restrict__ deg, float* __restrict__ dis){
  int n = blockIdx.x*256+threadIdx.x;
  if(n<NN){ float d=deg[n]; dis[n] = d>0.f ? rsqrtf(d) : 0.f; }
}

__global__ void k_wnorm(const int* __restrict__ src, const int* __restrict__ dst, const float* __restrict__ ea,
                        const float* __restrict__ dis, float* __restrict__ wnorm, int* __restrict__ cnt){
  int e = blockIdx.x*256+threadIdx.x;
  if(e<EE){
    int s=src[e], d=dst[e];
    wnorm[e] = dis[s]*ea[e]*dis[d];
    atomicAdd(&cnt[d],1);
  }
}

__global__ __launch_bounds__(1024) void k_scan(const int* __restrict__ cnt, int* __restrict__ rowptr, int* __restrict__ wp){
  __shared__ int wsum[16];
  __shared__ int carrysh;
  int tid=threadIdx.x, lane=tid&63, wv=tid>>6;
  if(tid==0){ carrysh=0; rowptr[0]=0; }
  __syncthreads();
  for(int base=0;base<NN;base+=1024){
    int i=base+tid;
    int v=(i<NN)?cnt[i]:0;
    int s=v;
    #pragma unroll
    for(int d=1;d<64;d<<=1){ int t=__shfl_up(s,d,64); if(lane>=d) s+=t; }
    if(lane==63) wsum[wv]=s;
    __syncthreads();
    if(wv==0 && lane<16){
      int t=wsum[lane]; int ss=t;
      #pragma unroll
      for(int d=1;d<16;d<<=1){ int u=__shfl_up(ss,d,64); if(lane>=d) ss+=u; }
      wsum[lane]=ss-t;
    }
    __syncthreads();
    int total = carrysh + wsum[wv] + s;
    if(i<NN) rowptr[i+1]=total;
    __syncthreads();
    if(tid==1023) carrysh = total;
    __syncthreads();
  }
  for(int i=tid;i<NN;i+=1024) wp[i]=rowptr[i];
}

__global__ void k_scatter(const int* __restrict__ src, const int* __restrict__ dst, const float* __restrict__ wnorm,
                          int* __restrict__ wp, int2* __restrict__ pack){
  int e = blockIdx.x*256+threadIdx.x;
  if(e<EE){
    int d=dst[e];
    int pos = atomicAdd(&wp[d],1);
    pack[pos] = make_int2(src[e], __float_as_int(wnorm[e]));
  }
}

// fetch original combined-K weights
__device__ __forceinline__ float fetchW1(const float* Wx, const float* Wh, int kk, int col){
  int g=col>>5, j=col&31;
  if(kk<160){ int k=kk>>5, i=kk&31; return Wx[((g*5+k)*32+i)*32+j]; }
  int rr=kk-160; int k=rr>>5, i=rr&31; return Wh[((g*5+k)*32+i)*32+j];
}
__device__ __forceinline__ float fetchW2(const float* Wx, const float* Wh, int kk, int col){
  int g=col>>4, j=col&15;
  if(kk<160){ int k=kk>>5, i=kk&31; return Wx[((g*5+k)*32+i)*16+j]; }
  if(kk<240){ int rr=kk-160; int k=rr>>4, i=rr&15; return Wh[((g*5+k)*16+i)*16+j]; }
  return 0.f;
}

// Pack W into MFMA B-fragments with k-map phi(kt,g,reg) = kt*32 + 8*g + reg.
// Wpk1: [kt(10)][s(2)][nt(8)][lane(64)] x 8 bf16 ; Wpk2: [kt(8)][s(2)][nt(4)][lane(64)] x 8 bf16
__global__ void k_wreorg(const float* __restrict__ Wx1,const float* __restrict__ bx1,
                         const float* __restrict__ Wh1,const float* __restrict__ bh1,const float* __restrict__ b1,
                         const float* __restrict__ Wx2,const float* __restrict__ bx2,
                         const float* __restrict__ Wh2,const float* __restrict__ bh2,const float* __restrict__ b2g,
                         short* __restrict__ Wpk1, short* __restrict__ Wpk2,
                         float* __restrict__ Bc1,float* __restrict__ Bc2){
  int idx = blockIdx.x*256+threadIdx.x;
  if(idx < 10240){
    int lane=idx&63, rest=idx>>6;
    int nt=rest&7, s=(rest>>3)&1, kt=rest>>4;
    int col = nt*16 + (lane&15);
    int g = lane>>4;
    short out[8];
    #pragma unroll
    for(int j=0;j<8;j++){
      int kk = kt*32 + 8*g + j;
      float w = fetchW1(Wx1,Wh1,kk,col);
      short hi = f2bf(w);
      out[j] = (s==0)? hi : f2bf(w - bf2f(hi));
    }
    #pragma unroll
    for(int j=0;j<8;j++) Wpk1[(size_t)idx*8+j]=out[j];
  } else if(idx < 14336){
    int t=idx-10240;
    int lane=t&63, rest=t>>6;
    int nt=rest&3, s=(rest>>2)&1, kt=rest>>3;
    int col = nt*16 + (lane&15);
    int g = lane>>4;
    short out[8];
    #pragma unroll
    for(int j=0;j<8;j++){
      int kk = kt*32 + 8*g + j;
      float w = fetchW2(Wx2,Wh2,kk,col);
      short hi = f2bf(w);
      out[j] = (s==0)? hi : f2bf(w - bf2f(hi));
    }
    #pragma unroll
    for(int j=0;j<8;j++) Wpk2[(size_t)t*8+j]=out[j];
  } else if(idx < 14464){
    int i=idx-14336; int g=i>>5,j=i&31;
    Bc1[i]=bx1[g*32+j]+bh1[g*32+j]+b1[g*32+j];
  } else if(idx < 14528){
    int i=idx-14464; int g=i>>4,j=i&15;
    Bc2[i]=bx2[g*16+j]+bh2[g*16+j]+b2g[g*16+j];
  }
}

// ---------- per-timestep ----------
// t=0 only: X slot of Z1
__global__ void k_init1(const float* __restrict__ xt, float* __restrict__ Z1){
  int idx=blockIdx.x*256+threadIdx.x;
  if(idx<NN*8){
    int n=idx>>3, c=idx&7;
    float4 v = ((const float4*)xt)[idx];
    *(float4*)&Z1[(size_t)n*320 + c*4] = v;
  }
}

// one wave per node; lane handles 2 channels (float2). lanes [0,NA/2): X chain, [NA/2, NA/2+NB/2): H chain
template<int STRIDE,int NA,int NB>
__global__ __launch_bounds__(256) void k_spmm(const int* __restrict__ rowptr, const int2* __restrict__ pack,
                       float* __restrict__ Z,
                       int cinA,int coutA,int cppA,int cinB,int coutB,int cppB,
                       float alpha,float beta){
  const int hA=NA/2, hB=NB/2;
  int wlocal = __builtin_amdgcn_readfirstlane(threadIdx.x>>6);
  int wid = blockIdx.x*4 + wlocal;
  if(wid>=NN) return;
  int lane = threadIdx.x&63;
  bool act = lane < hA+hB;
  int cin  = lane<hA ? cinA+2*lane : cinB+2*(lane-hA);
  int cout = lane<hA ? coutA+2*lane : coutB+2*(lane-hA);
  int cpp  = lane<hA ? cppA +2*lane : cppB+2*(lane-hA);
  if(!act) cin=0;
  const float* __restrict__ Zc = Z + cin;
  int e0=rowptr[wid], e1=rowptr[wid+1];
  float accx=0.f, accy=0.f;
  int e=e0;
  for(; e+16<=e1; e+=16){
    float w[16]; float2 z[16];
    #pragma unroll
    for(int j=0;j<16;j++){
      int2 p=pack[e+j];
      w[j]=__int_as_float(p.y);
      z[j]=*(const float2*)&Zc[(unsigned)p.x*STRIDE];
    }
    #pragma unroll
    for(int j=0;j<16;j++){ accx += w[j]*z[j].x; accy += w[j]*z[j].y; }
  }
  for(; e+4<=e1; e+=4){
    float w[4]; float2 z[4];
    #pragma unroll
    for(int j=0;j<4;j++){ int2 p=pack[e+j]; w[j]=__int_as_float(p.y); z[j]=*(const float2*)&Zc[(unsigned)p.x*STRIDE]; }
    #pragma unroll
    for(int j=0;j<4;j++){ accx += w[j]*z[j].x; accy += w[j]*z[j].y; }
  }
  for(; e<e1; ++e){
    int2 p=pack[e];
    float2 z=*(const float2*)&Zc[(unsigned)p.x*STRIDE];
    accx += __int_as_float(p.y)*z.x; accy += __int_as_float(p.y)*z.y;
  }
  if(act){
    float vx = -alpha*accx, vy = -alpha*accy;
    if(beta!=0.f){
      float2 pp=*(const float2*)&Z[(unsigned)wid*STRIDE+cpp];
      vx += beta*pp.x; vy += beta*pp.y;
    }
    *(float2*)&Z[(unsigned)wid*STRIDE+cout]=make_float2(vx,vy);
  }
}

// G1 = Z1[10000x320] @ W1[320x128] via MFMA bf16 3-term split; fused LSTM layer-1 epilogue.
// 625 blocks x 64 threads (1 wave), 16 rows each.
__global__ __launch_bounds__(64) void k_gemm1(float* __restrict__ Z1, const short* __restrict__ Wpk,
        const float* __restrict__ Bc, const float* __restrict__ wc1,
        float* __restrict__ c1, float* __restrict__ Z2){
  int lane=threadIdx.x;
  int row0=blockIdx.x*16;
  int m=lane&15, g=lane>>4;
  const float* arow = Z1 + (size_t)(row0+m)*320;
  const v8s* Wp = (const v8s*)Wpk;
  v4f acc[8];
  #pragma unroll
  for(int nt=0;nt<8;nt++) acc[nt]=(v4f){0.f,0.f,0.f,0.f};
  #pragma unroll
  for(int kt=0;kt<10;kt++){
    float4 a0=*(const float4*)&arow[kt*32+8*g];
    float4 a1=*(const float4*)&arow[kt*32+8*g+4];
    float av[8]={a0.x,a0.y,a0.z,a0.w,a1.x,a1.y,a1.z,a1.w};
    v8s ah, al;
    #pragma unroll
    for(int j=0;j<8;j++){
      short hi=f2bf(av[j]);
      ah[j]=hi; al[j]=f2bf(av[j]-bf2f(hi));
    }
    int baseh = kt*1024 + lane;   // [kt][s=0][nt][lane]
    #pragma unroll
    for(int nt=0;nt<8;nt++){
      v8s bh = Wp[baseh + nt*64];
      v8s bl = Wp[baseh + 512 + nt*64];
      acc[nt]=__builtin_amdgcn_mfma_f32_16x16x32_bf16(ah,bh,acc[nt],0,0,0);
      acc[nt]=__builtin_amdgcn_mfma_f32_16x16x32_bf16(al,bh,acc[nt],0,0,0);
      acc[nt]=__builtin_amdgcn_mfma_f32_16x16x32_bf16(ah,bl,acc[nt],0,0,0);
    }
  }
  // epilogue: C/D layout col=lane&15, row=(lane>>4)*4+reg
  int j0=lane&15;
  int r0=row0+(lane>>4)*4;
  #pragma unroll
  for(int reg=0;reg<4;reg++){
    int row=r0+reg;
    #pragma unroll
    for(int jj=0;jj<2;jj++){
      int j=jj*16+j0;
      float c=c1[row*32+j];
      float I =sigmf(acc[0+jj][reg]+Bc[j]      + wc1[j]*c);
      float Fg=sigmf(acc[2+jj][reg]+Bc[32+j]   + wc1[32+j]*c);
      float Ct=tanhf(acc[4+jj][reg]+Bc[64+j]);
      float Cn=Fg*c + I*Ct;
      float O =sigmf(acc[6+jj][reg]+Bc[96+j]   + wc1[64+j]*Cn);
      float h =O*tanhf(Cn);
      c1[row*32+j]=Cn;
      Z1[(size_t)row*320+160+j]=h;   // next-step layer-1 H-chain T0
      Z2[(size_t)row*240+j]=h;       // this-step layer-2 X-chain T0
    }
  }
}

// G2 = Z2[10000x240(pad256)] @ W2[256x64] via MFMA; fused LSTM layer-2 epilogue + x[t+1] copy.
__global__ __launch_bounds__(64) void k_gemm2(float* __restrict__ Z2, const short* __restrict__ Wpk,
        const float* __restrict__ Bc, const float* __restrict__ wc2,
        float* __restrict__ c2, float* __restrict__ h2,
        const float* __restrict__ xn, float* __restrict__ Z1){
  int lane=threadIdx.x;
  int row0=blockIdx.x*16;
  int m=lane&15, g=lane>>4;
  const float* arow = Z2 + (size_t)(row0+m)*240;
  const v8s* Wp = (const v8s*)Wpk;
  v4f acc[4];
  #pragma unroll
  for(int nt=0;nt<4;nt++) acc[nt]=(v4f){0.f,0.f,0.f,0.f};
  #pragma unroll
  for(int kt=0;kt<8;kt++){
    float4 a0=*(const float4*)&arow[kt*32+8*g];
    float4 a1=*(const float4*)&arow[kt*32+8*g+4];
    float av[8]={a0.x,a0.y,a0.z,a0.w,a1.x,a1.y,a1.z,a1.w};
    v8s ah, al;
    #pragma unroll
    for(int j=0;j<8;j++){
      short hi=f2bf(av[j]);
      ah[j]=hi; al[j]=f2bf(av[j]-bf2f(hi));
    }
    int baseh = kt*512 + lane;   // [kt][s(2)][nt(4)][lane]
    #pragma unroll
    for(int nt=0;nt<4;nt++){
      v8s bh = Wp[baseh + nt*64];
      v8s bl = Wp[baseh + 256 + nt*64];
      acc[nt]=__builtin_amdgcn_mfma_f32_16x16x32_bf16(ah,bh,acc[nt],0,0,0);
      acc[nt]=__builtin_amdgcn_mfma_f32_16x16x32_bf16(al,bh,acc[nt],0,0,0);
      acc[nt]=__builtin_amdgcn_mfma_f32_16x16x32_bf16(ah,bl,acc[nt],0,0,0);
    }
  }
  int j=lane&15;
  int r0=row0+(lane>>4)*4;
  #pragma unroll
  for(int reg=0;reg<4;reg++){
    int row=r0+reg;
    float c=c2[row*16+j];
    float I =sigmf(acc[0][reg]+Bc[j]    +wc2[j]*c);
    float Fg=sigmf(acc[1][reg]+Bc[16+j] +wc2[16+j]*c);
    float Ct=tanhf(acc[2][reg]+Bc[32+j]);
    float Cn=Fg*c+I*Ct;
    float O =sigmf(acc[3][reg]+Bc[48+j] +wc2[32+j]*Cn);
    float h =O*tanhf(Cn);
    c2[row*16+j]=Cn; h2[row*16+j]=h;
    Z2[(size_t)row*240+160+j]=h;     // next-step layer-2 H-chain T0
    if(xn){
      float2 xv=*(const float2*)&xn[(size_t)row*32+j*2];
      *(float2*)&Z1[(size_t)row*320+j*2]=xv;   // next-step layer-1 X-chain T0
    }
  }
}

// ---------- readout ----------
__global__ void k_pool(const float* __restrict__ h2, const int* __restrict__ batch, float* __restrict__ u){
  int idx=blockIdx.x*256+threadIdx.x;
  if(idx<NN*16){
    int n=idx>>4, j=idx&15;
    atomicAdd(&u[batch[n]*16+j], h2[idx]);
  }
}

__global__ void k_final(const float* __restrict__ u, const float* __restrict__ lw, const float* __restrict__ lb,
                        float* __restrict__ out){
  int g=threadIdx.x;
  if(g<NG){
    float s=lb[0];
    #pragma unroll
    for(int j=0;j<16;j++) s += u[g*16+j]*lw[j];
    out[g]=s;
  }
}

extern "C" void kernel_launch(void* const* d_in, const int* in_sizes, int n_in,
                              void* d_out, int out_size, void* d_ws, size_t ws_size,
                              hipStream_t stream){
  const float* x   = (const float*)d_in[0];
  const int*   ei  = (const int*)d_in[1];
  const float* ea  = (const float*)d_in[2];
  const int*   bat = (const int*)d_in[3];
  const float* Wx1=(const float*)d_in[4];  const float* bx1=(const float*)d_in[5];
  const float* Wh1=(const float*)d_in[6];  const float* bh1=(const float*)d_in[7];
  const float* wc1=(const float*)d_in[8];  const float* b1 =(const float*)d_in[9];
  const float* Wx2=(const float*)d_in[10]; const float* bx2=(const float*)d_in[11];
  const float* Wh2=(const float*)d_in[12]; const float* bh2=(const float*)d_in[13];
  const float* wc2=(const float*)d_in[14]; const float* b2 =(const float*)d_in[15];
  const float* lw =(const float*)d_in[16]; const float* lb =(const float*)d_in[17];
  const int* src = ei; const int* dst = ei+EE;

  float* ws = (float*)d_ws;
  size_t off=0;
  auto alloc=[&](size_t n)->float*{ float* p=ws+off; off+=(n+15)&~(size_t)15; return p; };
  // zeroed region: deg, c1, c2, u, cnt, Z1, Z2(+pad)
  float* deg=alloc(NN);
  float* c1=alloc((size_t)NN*32);
  float* c2=alloc((size_t)NN*16);
  float* u =alloc(NG*16);
  int*   cnt=(int*)alloc(NN);
  float* Z1=alloc((size_t)NN*320);
  float* Z2=alloc((size_t)NN*240+80);
  size_t zeroEnd=off;
  float* h2=alloc((size_t)NN*16);
  float* dis=alloc(NN);
  float* wnorm=alloc(EE);
  int*   rowptr=(int*)alloc(NN+1);
  int*   wp=(int*)alloc(NN);
  int2*  pack=(int2*)alloc((size_t)EE*2);
  short* Wpk1=(short*)alloc(10240*4);   // 10240 frags x 16B
  short* Wpk2=(short*)alloc(4096*4);
  float* Bc1=alloc(128);     float* Bc2=alloc(64);
  (void)ws_size; (void)in_sizes; (void)n_in; (void)out_size;

  hipMemsetAsync(d_ws, 0, zeroEnd*sizeof(float), stream);
  k_deg    <<<1250,256,0,stream>>>(src,ea,deg);
  k_dis    <<<40,256,0,stream>>>(deg,dis);
  k_wnorm  <<<1250,256,0,stream>>>(src,dst,ea,dis,wnorm,cnt);
  k_scan   <<<1,1024,0,stream>>>(cnt,rowptr,wp);
  k_scatter<<<1250,256,0,stream>>>(src,dst,wnorm,wp,pack);
  k_wreorg <<<57,256,0,stream>>>(Wx1,bx1,Wh1,bh1,b1,Wx2,bx2,Wh2,bh2,b2,Wpk1,Wpk2,Bc1,Bc2);

  k_init1<<<313,256,0,stream>>>(x, Z1);
  for(int t=0;t<TT;t++){
    for(int k=1;k<5;k++){
      float alpha = (k==1)?1.f:2.f, beta = (k==1)?0.f:-1.f;
      k_spmm<320,32,32><<<2500,256,0,stream>>>(rowptr,pack,Z1,
          (k-1)*32, k*32, (k-2)*32,
          160+(k-1)*32, 160+k*32, 160+(k-2)*32, alpha,beta);
    }
    k_gemm1<<<625,64,0,stream>>>(Z1,Wpk1,Bc1,wc1,c1,Z2);
    for(int k=1;k<5;k++){
      float alpha = (k==1)?1.f:2.f, beta = (k==1)?0.f:-1.f;
      k_spmm<240,32,16><<<2500,256,0,stream>>>(rowptr,pack,Z2,
          (k-1)*32, k*32, (k-2)*32,
          160+(k-1)*16, 160+k*16, 160+(k-2)*16, alpha,beta);
    }
    k_gemm2<<<625,64,0,stream>>>(Z2,Wpk2,Bc2,wc2,c2,h2,
          (t<TT-1)? x+(size_t)(t+1)*NN*32 : nullptr, Z1);
  }
  k_pool <<<625,256,0,stream>>>(h2,bat,u);
  k_final<<<1,64,0,stream>>>(u,lw,lb,(float*)d_out);
}